// Round 4
// baseline (715.347 us; speedup 1.0000x reference)
//
#include <hip/hip_runtime.h>

// Shapes: B=4, S=2048 -> M=8192; D_IN=K=4096; D_OUT=N=4096; R=16
constexpr int M = 8192;
constexpr int N = 4096;
constexpr int K = 4096;
constexpr float SCALING = 2.0f; // 32/16

typedef __bf16 bf16x8 __attribute__((ext_vector_type(8)));
typedef float  f32x4  __attribute__((ext_vector_type(4)));
typedef int    int32x4 __attribute__((ext_vector_type(4)));

// ---------------------------------------------------------------------------
// Kernel 1: per-row quantize x -> i8 + scale.  One block per row.
// xq[m,i] = round(x[m,i] * 127/max|row|),  sx[m] = max|row|/127
// ---------------------------------------------------------------------------
__global__ __launch_bounds__(256) void qlora_quant_x(const float* __restrict__ x,
                                                     char* __restrict__ xq,
                                                     float* __restrict__ sx) {
    const int m = blockIdx.x;
    const int t = threadIdx.x;
    const float4* row = (const float4*)(x + (size_t)m * K + t * 16);
    float4 v[4];
#pragma unroll
    for (int j = 0; j < 4; ++j) v[j] = row[j];

    float amax = 0.f;
#pragma unroll
    for (int j = 0; j < 4; ++j) {
        amax = fmaxf(amax, fabsf(v[j].x)); amax = fmaxf(amax, fabsf(v[j].y));
        amax = fmaxf(amax, fabsf(v[j].z)); amax = fmaxf(amax, fabsf(v[j].w));
    }
#pragma unroll
    for (int off = 32; off > 0; off >>= 1)
        amax = fmaxf(amax, __shfl_xor(amax, off, 64));
    __shared__ float red[4];
    if ((t & 63) == 0) red[t >> 6] = amax;
    __syncthreads();
    const float rmax = fmaxf(fmaxf(fmaxf(red[0], red[1]), fmaxf(red[2], red[3])), 1e-20f);
    const float q = 127.0f / rmax;
    if (t == 0) sx[m] = rmax / 127.0f;

    int32x4 p;
#pragma unroll
    for (int j = 0; j < 4; ++j) {
        const int b0 = __float2int_rn(v[j].x * q) & 0xFF;
        const int b1 = __float2int_rn(v[j].y * q) & 0xFF;
        const int b2 = __float2int_rn(v[j].z * q) & 0xFF;
        const int b3 = __float2int_rn(v[j].w * q) & 0xFF;
        p[j] = b0 | (b1 << 8) | (b2 << 16) | (b3 << 24);
    }
    ((int32x4*)(xq + (size_t)m * K))[t] = p;
}

// ---------------------------------------------------------------------------
// Kernel 2: w_int i32 -> i8 (exact; values already in [-128,127])
// ---------------------------------------------------------------------------
__global__ __launch_bounds__(256) void qlora_cast_w(const int* __restrict__ wi,
                                                    char* __restrict__ wq) {
    const size_t i = ((size_t)blockIdx.x * 256 + threadIdx.x) * 16;
    int32x4 p;
#pragma unroll
    for (int j = 0; j < 4; ++j) {
        const int32x4 a = *(const int32x4*)(wi + i + j * 4);
        p[j] = (a[0] & 0xFF) | ((a[1] & 0xFF) << 8) | ((a[2] & 0xFF) << 16) | ((a[3] & 0xFF) << 24);
    }
    *(int32x4*)(wq + i) = p;
}

// ---------------------------------------------------------------------------
// Kernel 3: T2[m,r] = 2 * dot(x[m,:], lA[r,:])  -> bf16 [M][16]
// Block handles 16 rows; thread (j=t>>4, r=t&15) computes one full dot.
// x reads broadcast within 16-lane groups; lA L1/L2-hot.
// ---------------------------------------------------------------------------
__global__ __launch_bounds__(256) void qlora_t2(const float* __restrict__ x,
                                                const float* __restrict__ lA,
                                                __bf16* __restrict__ T2) {
    const int j = threadIdx.x >> 4;
    const int r = threadIdx.x & 15;
    const size_t m = (size_t)blockIdx.x * 16 + j;
    const float4* xr = (const float4*)(x + m * K);
    const float4* ar = (const float4*)(lA + (size_t)r * K);
    float acc = 0.f;
#pragma unroll 4
    for (int i = 0; i < K / 4; ++i) {
        const float4 a = xr[i];
        const float4 b = ar[i];
        acc += a.x * b.x + a.y * b.y + a.z * b.z + a.w * b.w;
    }
    T2[m * 16 + r] = (__bf16)(SCALING * acc);
}

// ---------------------------------------------------------------------------
// Kernel 4: lB fp32 -> bf16 [N][16]
// ---------------------------------------------------------------------------
__global__ __launch_bounds__(256) void qlora_cast_lb(const float* __restrict__ lB,
                                                     __bf16* __restrict__ lBb) {
    const size_t i = ((size_t)blockIdx.x * 256 + threadIdx.x) * 8;
    const float4 v0 = *(const float4*)(lB + i);
    const float4 v1 = *(const float4*)(lB + i + 4);
    bf16x8 o;
    o[0] = (__bf16)v0.x; o[1] = (__bf16)v0.y; o[2] = (__bf16)v0.z; o[3] = (__bf16)v0.w;
    o[4] = (__bf16)v1.x; o[5] = (__bf16)v1.y; o[6] = (__bf16)v1.z; o[7] = (__bf16)v1.w;
    *(bf16x8*)(lBb + i) = o;
}

// ---------------------------------------------------------------------------
// Kernel 5: i8 GEMM  Ci32 = Xq[M,K] @ Wq[N,K]^T, BK=128 (32 iters),
// fused epilogue: out = Ci32*sx[m]*ws + T2@lBb^T (rank-16 via padded bf16 MFMA)
//
// LDS tile 128 rows x 128 B (i8). 16B chunk c of row r stored at slot c^(r&7);
// staging lane l -> row l>>3, slot l&7, global chunk (l&7)^(l>>3).
// Read: slot = (s*4+quad)^(lb&7) -> 2-way bank aliasing = free (m136).
// ---------------------------------------------------------------------------
__device__ __forceinline__ void async16(const char* g, char* l) {
    __builtin_amdgcn_global_load_lds(
        (const __attribute__((address_space(1))) unsigned int*)(unsigned long long)g,
        (__attribute__((address_space(3))) unsigned int*)(unsigned int)(unsigned long long)l,
        16, 0, 0);
}

__global__ __launch_bounds__(256) void qlora_gemm_i8(const char* __restrict__ Aq,
                                                     const char* __restrict__ Wq,
                                                     const float* __restrict__ sx,
                                                     const float* __restrict__ wscale,
                                                     const __bf16* __restrict__ T2,
                                                     const __bf16* __restrict__ lBb,
                                                     float* __restrict__ C) {
    __shared__ __align__(16) char As[128 * 128];
    __shared__ __align__(16) char Bs[128 * 128];

    const int tid  = threadIdx.x;
    const int w    = tid >> 6;
    const int lane = tid & 63;
    const int quad = lane >> 4;
    const int lb   = lane & 15;
    const int wm   = w >> 1;
    const int wn   = w & 1;

    const int r8   = lane >> 3;
    const int slot = lane & 7;
    const int q_sw = ((slot ^ r8) * 16);      // byte offset in 128-B row

    const size_t mBase = (size_t)blockIdx.y * 128;
    const size_t nBase = (size_t)blockIdx.x * 128;

    const char* gA[4]; const char* gB[4];
    char* lA[4]; char* lB[4];
#pragma unroll
    for (int j = 0; j < 4; ++j) {
        const int rt = w * 4 + j;
        gA[j] = Aq + (mBase + rt * 8 + r8) * K + q_sw;
        gB[j] = Wq + (nBase + rt * 8 + r8) * K + q_sw;
        lA[j] = As + rt * 1024;
        lB[j] = Bs + rt * 1024;
    }

    int32x4 acc[4][4] = {};

    for (int kt = 0; kt < K; kt += 128) {
#pragma unroll
        for (int j = 0; j < 4; ++j) async16(gA[j] + kt, lA[j]);
#pragma unroll
        for (int j = 0; j < 4; ++j) async16(gB[j] + kt, lB[j]);
        __syncthreads();

#pragma unroll
        for (int s = 0; s < 2; ++s) {
            int32x4 af[4], bfr[4];
#pragma unroll
            for (int t = 0; t < 4; ++t) {
                const int rowA = wm * 64 + t * 16 + lb;
                const int rowB = wn * 64 + t * 16 + lb;
                const int sl   = (((s * 4 + quad) ^ (lb & 7)) * 16);
                af[t]  = *(const int32x4*)(As + rowA * 128 + sl);
                bfr[t] = *(const int32x4*)(Bs + rowB * 128 + sl);
            }
#pragma unroll
            for (int tm = 0; tm < 4; ++tm)
#pragma unroll
                for (int tn = 0; tn < 4; ++tn)
                    acc[tm][tn] = __builtin_amdgcn_mfma_i32_16x16x64_i8(
                        af[tm], bfr[tn], acc[tm][tn], 0, 0, 0);
        }
        __syncthreads();
    }

    // ---- Epilogue staging: 256 rows x 64 B in As (rows 0..127 = T2 tile,
    // 128..255 = lB tile), each row = 16 bf16 data + 16 bf16 zero pad (k 16..31).
    // sx tile in Bs.
    {
        char* epi = As;
        const int row = tid;  // 0..255
        const int32x4 z = {0, 0, 0, 0};
        *(int32x4*)(epi + row * 64 + 32) = z;
        *(int32x4*)(epi + row * 64 + 48) = z;
        const char* src = (row < 128)
            ? ((const char*)T2  + (mBase + row) * 32)
            : ((const char*)lBb + (nBase + row - 128) * 32);
        *(int32x4*)(epi + row * 64)      = *(const int32x4*)(src);
        *(int32x4*)(epi + row * 64 + 16) = *(const int32x4*)(src + 16);
        float* sxs = (float*)Bs;
        if (tid < 128) sxs[tid] = sx[mBase + tid];
    }
    __syncthreads();

    const float wsv = wscale[0];
    const float* sxs = (const float*)Bs;
    const char*  epi = As;

    bf16x8 lbf[4];
#pragma unroll
    for (int tn = 0; tn < 4; ++tn) {
        const int nl = wn * 64 + tn * 16 + lb;
        lbf[tn] = *(const bf16x8*)(epi + (128 + nl) * 64 + quad * 16);
    }

#pragma unroll
    for (int tm = 0; tm < 4; ++tm) {
        const int ml = wm * 64 + tm * 16 + lb;
        const bf16x8 taf = *(const bf16x8*)(epi + ml * 64 + quad * 16);
        float sc[4];
#pragma unroll
        for (int j = 0; j < 4; ++j) sc[j] = sxs[wm * 64 + tm * 16 + quad * 4 + j] * wsv;

        const size_t m0 = mBase + wm * 64 + tm * 16 + quad * 4;
#pragma unroll
        for (int tn = 0; tn < 4; ++tn) {
            f32x4 fac;
#pragma unroll
            for (int j = 0; j < 4; ++j) fac[j] = (float)acc[tm][tn][j] * sc[j];
            // rank-16 LoRA add, padded to K=32 with zeros (verified mfma + layout)
            fac = __builtin_amdgcn_mfma_f32_16x16x32_bf16(taf, lbf[tn], fac, 0, 0, 0);

            const size_t n0 = nBase + wn * 64 + tn * 16 + lb;
            float* p = C + m0 * N + n0;
            p[0 * (size_t)N] = fac[0];
            p[1 * (size_t)N] = fac[1];
            p[2 * (size_t)N] = fac[2];
            p[3 * (size_t)N] = fac[3];
        }
    }
}

// ---------------------------------------------------------------------------
extern "C" void kernel_launch(void* const* d_in, const int* in_sizes, int n_in,
                              void* d_out, int out_size, void* d_ws, size_t ws_size,
                              hipStream_t stream) {
    const float* x      = (const float*)d_in[0];
    const int*   wint   = (const int*)d_in[1];
    const float* wscale = (const float*)d_in[2];
    const float* lA     = (const float*)d_in[3];
    const float* lB     = (const float*)d_in[4];
    float* out = (float*)d_out;

    char* ws = (char*)d_ws;
    char*    Xq  = ws;                                  // 32 MiB
    char*    Wq  = ws + (size_t)M * K;                  // 16 MiB
    float*   Sx  = (float*)(ws + (size_t)(M + N) * K);  // 32 KiB
    __bf16*  T2  = (__bf16*)(ws + (size_t)(M + N) * K + 32768);           // 256 KiB
    __bf16*  LBb = (__bf16*)(ws + (size_t)(M + N) * K + 32768 + 262144);  // 128 KiB

    qlora_quant_x<<<M, 256, 0, stream>>>(x, Xq, Sx);
    qlora_cast_w<<<(size_t)N * K / (256 * 16), 256, 0, stream>>>(wint, Wq);
    qlora_t2<<<M / 16, 256, 0, stream>>>(x, lA, T2);
    qlora_cast_lb<<<N * 16 / (256 * 8), 256, 0, stream>>>(lB, LBb);
    qlora_gemm_i8<<<dim3(N / 128, M / 128), 256, 0, stream>>>(Xq, Wq, Sx, wscale, T2, LBb, out);
}